// Round 5
// baseline (258.598 us; speedup 1.0000x reference)
//
#include <hip/hip_runtime.h>
#include <cmath>
#include <cstdint>

#define NB 8
#define NPTS 4096
#define NPOINT 204
#define NCENT (NB * NPOINT)   // 1632
#define NTASK (5 * NCENT)     // 8160

typedef unsigned long long u64;

struct BallParams { float thr[5]; int ns[5]; float el; float denom; };
struct FinalParams { double w[5]; };

// ---------------------------------------------------------------------------
// u64 max DPP reduction: row_shr 1/2/4/8 + row_bcast15/31 -> lane 63 holds max.
// ---------------------------------------------------------------------------
template<int CTRL, int RMASK>
__device__ __forceinline__ u64 dpp_u64max_step(u64 v) {
    const int lo = (int)(unsigned)v, hi = (int)(unsigned)(v >> 32);
    const int lo2 = __builtin_amdgcn_update_dpp(lo, lo, CTRL, RMASK, 0xF, false);
    const int hi2 = __builtin_amdgcn_update_dpp(hi, hi, CTRL, RMASK, 0xF, false);
    const u64 o = ((u64)(unsigned)hi2 << 32) | (unsigned)lo2;
    return o > v ? o : v;
}
__device__ __forceinline__ u64 wave_u64max63(u64 v) {
    v = dpp_u64max_step<0x111, 0xF>(v);   // row_shr:1
    v = dpp_u64max_step<0x112, 0xF>(v);   // row_shr:2
    v = dpp_u64max_step<0x114, 0xF>(v);   // row_shr:4
    v = dpp_u64max_step<0x118, 0xF>(v);   // row_shr:8
    v = dpp_u64max_step<0x142, 0xA>(v);   // row_bcast:15
    v = dpp_u64max_step<0x143, 0xC>(v);   // row_bcast:31
    return v;                              // lane 63 = wave max
}
__device__ __forceinline__ u64 u64max(u64 a, u64 b) { return a > b ? a : b; }

// ---------------------------------------------------------------------------
// Fused: blocks 0..7 FPS (one batch, 16 waves, 4 pts/lane);
// blocks 8..519 repulsion (4 pts/wave).
// ---------------------------------------------------------------------------
__global__ __launch_bounds__(1024) void fused_fps_rep(const float* __restrict__ pcd,
                                                      int* __restrict__ fps,
                                                      double* __restrict__ part)
{
#pragma clang fp contract(off)
    __shared__ float4 spts[NPTS];                 // 64 KiB
    __shared__ int fps_lds[NPOINT];
    __shared__ __align__(16) u64 exch[2][16];
    __shared__ double wsum[16];

    const int t = threadIdx.x;
    const int lane = t & 63, wv = t >> 6;

    if (blockIdx.x < NB) {
        // ------------------------------ FPS ------------------------------
        const int b = blockIdx.x;
        const float* base = pcd + (size_t)b * NPTS * 3;

        for (int j = t; j < NPTS; j += 1024)
            spts[j] = make_float4(base[3*j], base[3*j+1], base[3*j+2], 0.f);

        const int pbase = t * 4;
        float px[4], py[4], pz[4], md[4];
#pragma unroll
        for (int k = 0; k < 4; ++k) {
            px[k] = base[(pbase + k) * 3 + 0];
            py[k] = base[(pbase + k) * 3 + 1];
            pz[k] = base[(pbase + k) * 3 + 2];
            md[k] = 1e10f;
        }
        if (t == 0) fps_lds[0] = 0;
        __syncthreads();

        float lx = spts[0].x, ly = spts[0].y, lz = spts[0].z;

        for (int it = 1; it < NPOINT; ++it) {
            u64 c[4];
            // exact per-element: (dx^2+dy^2)+dz^2, fminf; pack (bits(md)<<32)|(4095-idx)
#pragma unroll
            for (int k = 0; k < 4; ++k) {
                const float dx = px[k] - lx, dy = py[k] - ly, dz = pz[k] - lz;
                float d = dx * dx + dy * dy;
                d = d + dz * dz;
                const float m = fminf(md[k], d);
                md[k] = m;
                c[k] = ((u64)(unsigned)__float_as_int(m) << 32)
                     | (unsigned)(4095 - (pbase + k));
            }
            c[0] = u64max(c[0], c[2]);
            c[1] = u64max(c[1], c[3]);
            c[0] = u64max(c[0], c[1]);
            const u64 wmax = wave_u64max63(c[0]);

            if (lane == 63) exch[it & 1][wv] = wmax;
            __syncthreads();

            const ulonglong2* e = (const ulonglong2*)&exch[it & 1][0];
            u64 r0 = u64max(e[0].x, e[0].y);
            u64 r1 = u64max(e[1].x, e[1].y);
            u64 r2 = u64max(e[2].x, e[2].y);
            u64 r3 = u64max(e[3].x, e[3].y);
            u64 r4 = u64max(e[4].x, e[4].y);
            u64 r5 = u64max(e[5].x, e[5].y);
            u64 r6 = u64max(e[6].x, e[6].y);
            u64 r7 = u64max(e[7].x, e[7].y);
            r0 = u64max(r0, r1); r2 = u64max(r2, r3);
            r4 = u64max(r4, r5); r6 = u64max(r6, r7);
            r0 = u64max(r0, r2); r4 = u64max(r4, r6);
            const u64 m = u64max(r0, r4);
            const int bi = 4095 - (int)((unsigned)m & 0xFFFu);

            if (t == 0) fps_lds[it] = bi;
            const float4 cc = spts[bi];
            lx = cc.x; ly = cc.y; lz = cc.z;
        }
        __syncthreads();
        for (int j = t; j < NPOINT; j += 1024) fps[b * NPOINT + j] = fps_lds[j];
    } else {
        // --------------------------- repulsion ---------------------------
        const int bb = blockIdx.x - NB;
        const int batch = bb >> 6;
        const int chunk = bb & 63;
        const float* base = pcd + (size_t)batch * NPTS * 3;

        for (int j = t; j < NPTS; j += 1024) {
            const float x = base[j * 3 + 0], y = base[j * 3 + 1], z = base[j * 3 + 2];
            const float qs = (x * x + y * y) + z * z;
            spts[j] = make_float4(x, y, z, qs);
        }
        __syncthreads();

        const float h = 0.0005f;
        double acc = 0.0;

        for (int ii = 0; ii < 4; ++ii) {
            const int i = (chunk << 6) + (wv << 2) + ii;
            const float4 C = spts[i];
            const float cx = C.x, cy = C.y, cz = C.z, cs = C.w;
            float s0 = 3e38f, s1 = 3e38f, s2 = 3e38f, s3 = 3e38f;
            for (int bj = 0; bj < NPTS; bj += 64) {
                const int j = bj + lane;
                const float4 o = spts[j];
                const float dot = (cx * o.x + cy * o.y) + cz * o.z;
                const float d = fmaxf((cs + o.w) - 2.0f * dot, 0.0f);
                const bool q = (d < h) && (j != i);
                unsigned long long bal = __ballot(q);
                while (bal) {
                    const int src = __ffsll((unsigned long long)bal) - 1;
                    bal &= bal - 1;
                    const float dv = __shfl(d, src);
                    if (dv < s0) { s3 = s2; s2 = s1; s1 = s0; s0 = dv; }
                    else if (dv < s1) { s3 = s2; s2 = s1; s1 = dv; }
                    else if (dv < s2) { s3 = s2; s2 = dv; }
                    else if (dv < s3) { s3 = dv; }
                }
            }
            if (lane == 0) {
                if (s0 < h) acc += (double)(h - s0);
                if (s1 < h) acc += (double)(h - s1);
                if (s2 < h) acc += (double)(h - s2);
                if (s3 < h) acc += (double)(h - s3);
            }
        }
        if (lane == 0) wsum[wv] = acc;
        __syncthreads();
        if (t == 0) {
            double s = 0.0;
            for (int w = 0; w < 16; ++w) s += wsum[w];
            part[bb] = s;
        }
    }
}

// ---------------------------------------------------------------------------
// Ball query + per-group uniform term. 4 waves/block; all 4 tasks of a block
// share one (p, batch) since NPOINT%4==0 -> shared LDS staging of the batch.
// ---------------------------------------------------------------------------
__global__ __launch_bounds__(256) void ball_kernel(const float* __restrict__ pcd,
                                                   const int* __restrict__ fps,
                                                   double* __restrict__ uvals,
                                                   BallParams P)
{
#pragma clang fp contract(off)
    __shared__ float4 spts[NPTS];        // 64 KiB: x,y,z,|q|^2
    __shared__ int wlist[4][64];
    __shared__ float4 gpts[4][64];

    const int wave = threadIdx.x >> 6;
    const int lane = threadIdx.x & 63;
    const int task0 = blockIdx.x * 4;            // all 4 tasks: same pi, same b
    const int pi = task0 / NCENT;
    const int c0 = task0 % NCENT;
    const int b  = c0 / NPOINT;
    const int   nsample = P.ns[pi];
    const float thr     = P.thr[pi];

    const float* base = pcd + (size_t)b * NPTS * 3;
    for (int j = threadIdx.x; j < NPTS; j += 256) {
        const float x = base[j * 3 + 0], y = base[j * 3 + 1], z = base[j * 3 + 2];
        const float qs = (x * x + y * y) + z * z;
        spts[j] = make_float4(x, y, z, qs);
    }
    __syncthreads();

    const int c = c0 + wave;
    const int m = c % NPOINT;
    const int ci = fps[b * NPOINT + m];
    const float4 C = spts[ci];
    const float cx = C.x, cy = C.y, cz = C.z, cs = C.w;

    int cnt = 0;
    for (int bj = 0; bj < NPTS; bj += 64) {
        const int j = bj + lane;
        const float4 o = spts[j];
        const float dot = (cx * o.x + cy * o.y) + cz * o.z;
        const float d = fmaxf((cs + o.w) - 2.0f * dot, 0.0f);
        const bool q = d < thr;
        const unsigned long long bal = __ballot(q);
        if (q) {
            const int pos = cnt + __popcll(bal & ((1ull << lane) - 1ull));
            if (pos < nsample) wlist[wave][pos] = j;
        }
        cnt += __popcll(bal);
        if (cnt >= nsample) break;
    }
    const int m_in = (cnt < nsample) ? cnt : nsample;   // >= 1 (center inside)

    const int gidx = wlist[wave][(lane < m_in) ? lane : 0];
    const float4 G = spts[gidx];
    gpts[wave][lane] = G;
    const float gx = G.x, gy = G.y, gz = G.z, gs = G.w;

    float m1 = 3.0e38f, m2 = 3.0e38f;
    for (int j = 0; j < nsample; ++j) {
        const float4 o = gpts[wave][j];
        const float dot = (gx * o.x + gy * o.y) + gz * o.z;
        const float d = fmaxf((gs + o.w) - 2.0f * dot, 0.0f);
        if (d < m1) { m2 = m1; m1 = d; }
        else if (d < m2) { m2 = d; }
    }
    float ud = (lane < nsample) ? fabsf(sqrtf(m2 + 1e-12f) + 1e-8f) : 0.0f;
    for (int off = 32; off; off >>= 1) ud += __shfl_xor(ud, off);
    if (lane == 0) {
        const float um   = ud / (float)nsample;
        const float diff = um - P.el;
        const float u    = (diff * diff) / P.denom;
        uvals[pi * NCENT + c] = (double)u;
    }
}

// ---------------------------------------------------------------------------
// Deterministic final reduction + loss assembly.
// ---------------------------------------------------------------------------
__global__ __launch_bounds__(256) void final_kernel(const double* __restrict__ uvals,
                                                    const double* __restrict__ part,
                                                    float* __restrict__ out,
                                                    FinalParams F)
{
    __shared__ double red[256];
    const int t = threadIdx.x;
    double sums[6];

    for (int p = 0; p < 5; ++p) {
        double s = 0.0;
        for (int c = t; c < NCENT; c += 256) s += uvals[p * NCENT + c];
        red[t] = s;
        __syncthreads();
        for (int o = 128; o; o >>= 1) {
            if (t < o) red[t] += red[t + o];
            __syncthreads();
        }
        if (t == 0) sums[p] = red[0];
        __syncthreads();
    }
    {
        double s = 0.0;
        for (int c = t; c < NB * 64; c += 256) s += part[c];
        red[t] = s;
        __syncthreads();
        for (int o = 128; o; o >>= 1) {
            if (t < o) red[t] += red[t + o];
            __syncthreads();
        }
        if (t == 0) sums[5] = red[0];
    }
    if (t == 0) {
        double loss = 0.0;
        loss += (sums[0] / (double)NCENT) * F.w[0];
        loss += (sums[1] / (double)NCENT) * F.w[1];
        loss += (sums[2] / (double)NCENT) * F.w[2];
        loss += (sums[3] / (double)NCENT) * F.w[3];
        loss += (sums[4] / (double)NCENT) * F.w[4];
        loss /= 5.0;
        const double rep = sums[5] / (double)(NB * NPTS * 4);
        out[0] = (float)(loss + rep);
    }
}

// ---------------------------------------------------------------------------
extern "C" void kernel_launch(void* const* d_in, const int* in_sizes, int n_in,
                              void* d_out, int out_size, void* d_ws, size_t ws_size,
                              hipStream_t stream)
{
    const float* pcd = (const float*)d_in[0];
    float* out = (float*)d_out;

    int*    fps   = (int*)d_ws;                                   // NB*NPOINT ints
    double* uvals = (double*)((char*)d_ws + 8192);                // 5*NCENT doubles
    double* repp  = (double*)((char*)d_ws + 8192 + (size_t)5 * NCENT * 8); // NB*64 doubles

    const double pv[5] = {0.004, 0.006, 0.008, 0.01, 0.012};
    const int    nsv[5] = {16, 24, 32, 40, 49};

    BallParams bp;
    FinalParams fp;
    for (int i = 0; i < 5; ++i) {
        const double r = sqrt(pv[i]);
        bp.thr[i] = (float)(r * r);
        bp.ns[i]  = nsv[i];
        const double w = pv[i] * 100.0;
        fp.w[i] = w * w;
    }
    const double el = sqrt(3.141592653589793 / 4096.0);
    bp.el    = (float)el;
    bp.denom = (float)(el + 1e-8);

    fused_fps_rep<<<NB + NB * 64, 1024, 0, stream>>>(pcd, fps, repp);
    ball_kernel<<<NTASK / 4, 256, 0, stream>>>(pcd, fps, uvals, bp);
    final_kernel<<<1, 256, 0, stream>>>(uvals, repp, out, fp);
}

// Round 6
// 220.520 us; speedup vs baseline: 1.1727x; 1.1727x over previous
//
#include <hip/hip_runtime.h>
#include <cmath>
#include <cstdint>

#define NB 8
#define NPTS 4096
#define NPOINT 204
#define NCENT (NB * NPOINT)   // 1632
#define NTASK (5 * NCENT)     // 8160

typedef unsigned long long u64;
typedef float v2f __attribute__((ext_vector_type(2)));

struct BallParams { float thr[5]; int ns[5]; float el; float denom; };
struct FinalParams { double w[5]; };

// ---------------------------------------------------------------------------
// u64 max DPP reduction: row_shr 1/2/4/8 + row_bcast15/31 -> lane 63 holds max.
// ---------------------------------------------------------------------------
template<int CTRL, int RMASK>
__device__ __forceinline__ u64 dpp_u64max_step(u64 v) {
    const int lo = (int)(unsigned)v, hi = (int)(unsigned)(v >> 32);
    const int lo2 = __builtin_amdgcn_update_dpp(lo, lo, CTRL, RMASK, 0xF, false);
    const int hi2 = __builtin_amdgcn_update_dpp(hi, hi, CTRL, RMASK, 0xF, false);
    const u64 o = ((u64)(unsigned)hi2 << 32) | (unsigned)lo2;
    return o > v ? o : v;
}
__device__ __forceinline__ u64 wave_u64max63(u64 v) {
    v = dpp_u64max_step<0x111, 0xF>(v);   // row_shr:1
    v = dpp_u64max_step<0x112, 0xF>(v);   // row_shr:2
    v = dpp_u64max_step<0x114, 0xF>(v);   // row_shr:4
    v = dpp_u64max_step<0x118, 0xF>(v);   // row_shr:8
    v = dpp_u64max_step<0x142, 0xA>(v);   // row_bcast:15
    v = dpp_u64max_step<0x143, 0xC>(v);   // row_bcast:31
    return v;                              // lane 63 = wave max
}
__device__ __forceinline__ u64 u64max(u64 a, u64 b) { return a > b ? a : b; }

// ---------------------------------------------------------------------------
// Fused: blocks 0..7 FPS (one batch, 8 waves, 8 pts/lane);
// blocks 8..519 repulsion. LDS padded to ~96KB so ONLY ONE block fits per CU:
// FPS blocks must not share their CU with issue-hungry rep blocks (the
// co-residency contention was the hidden 2x on the FPS critical path).
// ---------------------------------------------------------------------------
__global__ __launch_bounds__(512) void fused_fps_rep(const float* __restrict__ pcd,
                                                     int* __restrict__ fps,
                                                     double* __restrict__ part)
{
#pragma clang fp contract(off)
    __shared__ float4 spts[NPTS + 2048];          // 96 KiB (pad -> 1 block/CU)
    __shared__ int fps_lds[NPOINT];
    __shared__ __align__(16) u64 exch[2][8];
    __shared__ double wsum[8];

    const int t = threadIdx.x;
    const int lane = t & 63, wv = t >> 6;

    if (blockIdx.x < NB) {
        // ------------------------------ FPS ------------------------------
        const int b = blockIdx.x;
        const float* base = pcd + (size_t)b * NPTS * 3;

        for (int j = t; j < NPTS; j += 512)
            spts[j] = make_float4(base[3*j], base[3*j+1], base[3*j+2], 0.f);

        const int pbase = t * 8;
        v2f px2[4], py2[4], pz2[4], md2[4];
#pragma unroll
        for (int i = 0; i < 4; ++i) {
            const int k0 = pbase + 2 * i, k1 = k0 + 1;
            px2[i] = (v2f){ base[k0*3+0], base[k1*3+0] };
            py2[i] = (v2f){ base[k0*3+1], base[k1*3+1] };
            pz2[i] = (v2f){ base[k0*3+2], base[k1*3+2] };
            md2[i] = (v2f){ 1e10f, 1e10f };
        }
        if (t == 0) fps_lds[0] = 0;
        __syncthreads();

        float lx = spts[0].x, ly = spts[0].y, lz = spts[0].z;

        for (int it = 1; it < NPOINT; ++it) {
            const v2f lx2 = (v2f){lx, lx}, ly2 = (v2f){ly, ly}, lz2 = (v2f){lz, lz};
            u64 c[8];
            // exact per-element (pk ops are element-wise): (dx^2+dy^2)+dz^2, fminf
#pragma unroll
            for (int i = 0; i < 4; ++i) {
                const v2f dx = px2[i] - lx2, dy = py2[i] - ly2, dz = pz2[i] - lz2;
                v2f d = dx * dx + dy * dy;
                d = d + dz * dz;
                v2f m = md2[i];
                m.x = fminf(m.x, d.x);
                m.y = fminf(m.y, d.y);
                md2[i] = m;
                c[2*i]   = ((u64)(unsigned)__float_as_int(m.x) << 32)
                         | (unsigned)(4095 - (pbase + 2*i));
                c[2*i+1] = ((u64)(unsigned)__float_as_int(m.y) << 32)
                         | (unsigned)(4095 - (pbase + 2*i + 1));
            }
#pragma unroll
            for (int s = 4; s >= 1; s >>= 1)
#pragma unroll
                for (int i = 0; i < 8; ++i)
                    if (i < s) c[i] = u64max(c[i], c[i + s]);
            const u64 wmax = wave_u64max63(c[0]);

            if (lane == 63) exch[it & 1][wv] = wmax;
            __syncthreads();

            const ulonglong2* e = (const ulonglong2*)&exch[it & 1][0];
            const ulonglong2 E0 = e[0], E1 = e[1], E2 = e[2], E3 = e[3];
            u64 m01 = u64max(E0.x, E0.y), m23 = u64max(E1.x, E1.y);
            u64 m45 = u64max(E2.x, E2.y), m67 = u64max(E3.x, E3.y);
            const u64 m = u64max(u64max(m01, m23), u64max(m45, m67));
            const int bi = 4095 - (int)((unsigned)m & 0xFFFu);

            if (t == 0) fps_lds[it] = bi;
            const float4 cc = spts[bi];
            lx = cc.x; ly = cc.y; lz = cc.z;
        }
        __syncthreads();
        for (int j = t; j < NPOINT; j += 512) fps[b * NPOINT + j] = fps_lds[j];
    } else {
        // --------------------------- repulsion ---------------------------
        const int bb = blockIdx.x - NB;
        const int batch = bb >> 6;
        const int chunk = bb & 63;
        const float* base = pcd + (size_t)batch * NPTS * 3;

        for (int j = t; j < NPTS; j += 512) {
            const float x = base[j * 3 + 0], y = base[j * 3 + 1], z = base[j * 3 + 2];
            const float qs = (x * x + y * y) + z * z;
            spts[j] = make_float4(x, y, z, qs);
        }
        __syncthreads();

        const float h = 0.0005f;
        double acc = 0.0;

        for (int ii = 0; ii < 8; ++ii) {
            const int i = (chunk << 6) + (wv << 3) + ii;
            const float4 C = spts[i];
            const float cx = C.x, cy = C.y, cz = C.z, cs = C.w;
            float s0 = 3e38f, s1 = 3e38f, s2 = 3e38f, s3 = 3e38f;
            for (int bj = 0; bj < NPTS; bj += 64) {
                const int j = bj + lane;
                const float4 o = spts[j];
                const float dot = (cx * o.x + cy * o.y) + cz * o.z;
                const float d = fmaxf((cs + o.w) - 2.0f * dot, 0.0f);
                const bool q = (d < h) && (j != i);
                unsigned long long bal = __ballot(q);
                while (bal) {
                    const int src = __ffsll((unsigned long long)bal) - 1;
                    bal &= bal - 1;
                    const float dv = __shfl(d, src);
                    if (dv < s0) { s3 = s2; s2 = s1; s1 = s0; s0 = dv; }
                    else if (dv < s1) { s3 = s2; s2 = s1; s1 = dv; }
                    else if (dv < s2) { s3 = s2; s2 = dv; }
                    else if (dv < s3) { s3 = dv; }
                }
            }
            if (lane == 0) {
                if (s0 < h) acc += (double)(h - s0);
                if (s1 < h) acc += (double)(h - s1);
                if (s2 < h) acc += (double)(h - s2);
                if (s3 < h) acc += (double)(h - s3);
            }
        }
        if (lane == 0) wsum[wv] = acc;
        __syncthreads();
        if (t == 0) {
            double s = 0.0;
            for (int w = 0; w < 8; ++w) s += wsum[w];
            part[bb] = s;
        }
    }
}

// ---------------------------------------------------------------------------
// Ball query + per-group uniform term. 4 waves/block; all 4 tasks of a block
// share one (p, batch) since NPOINT%4==0 -> shared LDS staging of the batch.
// ---------------------------------------------------------------------------
__global__ __launch_bounds__(256) void ball_kernel(const float* __restrict__ pcd,
                                                   const int* __restrict__ fps,
                                                   double* __restrict__ uvals,
                                                   BallParams P)
{
#pragma clang fp contract(off)
    __shared__ float4 spts[NPTS];        // 64 KiB: x,y,z,|q|^2
    __shared__ int wlist[4][64];
    __shared__ float4 gpts[4][64];

    const int wave = threadIdx.x >> 6;
    const int lane = threadIdx.x & 63;
    const int task0 = blockIdx.x * 4;            // all 4 tasks: same pi, same b
    const int pi = task0 / NCENT;
    const int c0 = task0 % NCENT;
    const int b  = c0 / NPOINT;
    const int   nsample = P.ns[pi];
    const float thr     = P.thr[pi];

    const float* base = pcd + (size_t)b * NPTS * 3;
    for (int j = threadIdx.x; j < NPTS; j += 256) {
        const float x = base[j * 3 + 0], y = base[j * 3 + 1], z = base[j * 3 + 2];
        const float qs = (x * x + y * y) + z * z;
        spts[j] = make_float4(x, y, z, qs);
    }
    __syncthreads();

    const int c = c0 + wave;
    const int m = c % NPOINT;
    const int ci = fps[b * NPOINT + m];
    const float4 C = spts[ci];
    const float cx = C.x, cy = C.y, cz = C.z, cs = C.w;

    int cnt = 0;
    for (int bj = 0; bj < NPTS; bj += 64) {
        const int j = bj + lane;
        const float4 o = spts[j];
        const float dot = (cx * o.x + cy * o.y) + cz * o.z;
        const float d = fmaxf((cs + o.w) - 2.0f * dot, 0.0f);
        const bool q = d < thr;
        const unsigned long long bal = __ballot(q);
        if (q) {
            const int pos = cnt + __popcll(bal & ((1ull << lane) - 1ull));
            if (pos < nsample) wlist[wave][pos] = j;
        }
        cnt += __popcll(bal);
        if (cnt >= nsample) break;
    }
    const int m_in = (cnt < nsample) ? cnt : nsample;   // >= 1 (center inside)

    const int gidx = wlist[wave][(lane < m_in) ? lane : 0];
    const float4 G = spts[gidx];
    gpts[wave][lane] = G;
    const float gx = G.x, gy = G.y, gz = G.z, gs = G.w;

    float m1 = 3.0e38f, m2 = 3.0e38f;
    for (int j = 0; j < nsample; ++j) {
        const float4 o = gpts[wave][j];
        const float dot = (gx * o.x + gy * o.y) + gz * o.z;
        const float d = fmaxf((gs + o.w) - 2.0f * dot, 0.0f);
        if (d < m1) { m2 = m1; m1 = d; }
        else if (d < m2) { m2 = d; }
    }
    float ud = (lane < nsample) ? fabsf(sqrtf(m2 + 1e-12f) + 1e-8f) : 0.0f;
    for (int off = 32; off; off >>= 1) ud += __shfl_xor(ud, off);
    if (lane == 0) {
        const float um   = ud / (float)nsample;
        const float diff = um - P.el;
        const float u    = (diff * diff) / P.denom;
        uvals[pi * NCENT + c] = (double)u;
    }
}

// ---------------------------------------------------------------------------
// Deterministic final reduction + loss assembly.
// ---------------------------------------------------------------------------
__global__ __launch_bounds__(256) void final_kernel(const double* __restrict__ uvals,
                                                    const double* __restrict__ part,
                                                    float* __restrict__ out,
                                                    FinalParams F)
{
    __shared__ double red[256];
    const int t = threadIdx.x;
    double sums[6];

    for (int p = 0; p < 5; ++p) {
        double s = 0.0;
        for (int c = t; c < NCENT; c += 256) s += uvals[p * NCENT + c];
        red[t] = s;
        __syncthreads();
        for (int o = 128; o; o >>= 1) {
            if (t < o) red[t] += red[t + o];
            __syncthreads();
        }
        if (t == 0) sums[p] = red[0];
        __syncthreads();
    }
    {
        double s = 0.0;
        for (int c = t; c < NB * 64; c += 256) s += part[c];
        red[t] = s;
        __syncthreads();
        for (int o = 128; o; o >>= 1) {
            if (t < o) red[t] += red[t + o];
            __syncthreads();
        }
        if (t == 0) sums[5] = red[0];
    }
    if (t == 0) {
        double loss = 0.0;
        loss += (sums[0] / (double)NCENT) * F.w[0];
        loss += (sums[1] / (double)NCENT) * F.w[1];
        loss += (sums[2] / (double)NCENT) * F.w[2];
        loss += (sums[3] / (double)NCENT) * F.w[3];
        loss += (sums[4] / (double)NCENT) * F.w[4];
        loss /= 5.0;
        const double rep = sums[5] / (double)(NB * NPTS * 4);
        out[0] = (float)(loss + rep);
    }
}

// ---------------------------------------------------------------------------
extern "C" void kernel_launch(void* const* d_in, const int* in_sizes, int n_in,
                              void* d_out, int out_size, void* d_ws, size_t ws_size,
                              hipStream_t stream)
{
    const float* pcd = (const float*)d_in[0];
    float* out = (float*)d_out;

    int*    fps   = (int*)d_ws;                                   // NB*NPOINT ints
    double* uvals = (double*)((char*)d_ws + 8192);                // 5*NCENT doubles
    double* repp  = (double*)((char*)d_ws + 8192 + (size_t)5 * NCENT * 8); // NB*64 doubles

    const double pv[5] = {0.004, 0.006, 0.008, 0.01, 0.012};
    const int    nsv[5] = {16, 24, 32, 40, 49};

    BallParams bp;
    FinalParams fp;
    for (int i = 0; i < 5; ++i) {
        const double r = sqrt(pv[i]);
        bp.thr[i] = (float)(r * r);
        bp.ns[i]  = nsv[i];
        const double w = pv[i] * 100.0;
        fp.w[i] = w * w;
    }
    const double el = sqrt(3.141592653589793 / 4096.0);
    bp.el    = (float)el;
    bp.denom = (float)(el + 1e-8);

    fused_fps_rep<<<NB + NB * 64, 512, 0, stream>>>(pcd, fps, repp);
    ball_kernel<<<NTASK / 4, 256, 0, stream>>>(pcd, fps, uvals, bp);
    final_kernel<<<1, 256, 0, stream>>>(uvals, repp, out, fp);
}